// Round 10
// baseline (224.494 us; speedup 1.0000x reference)
//
#include <hip/hip_runtime.h>

#define NNODES 200000
#define NEDGES 3200000
#define NGRAPH 100
#define NPG    2000
#define D      128
#define DOUT   64
#define CAP1   4096     // max distinct layer-1 nodes (expected ~1600)
#define CAP2   8192     // max edges into fetched nodes (expected ~1600)
#define CAPE   65536    // max edges into S1 nodes (expected ~25600)
#define FBUF   1024     // per-block LDS compaction buffer
#define NBLK   768      // 3 blocks/CU -> co-resident with launch_bounds(256,4)
#define BLINES 8        // barrier counter lines

// coherent (IC-bypass) store/load helpers: no fences, no L2 flush
__device__ __forceinline__ void stg(int* p, int v) {
    __hip_atomic_store(p, v, __ATOMIC_RELAXED, __HIP_MEMORY_SCOPE_AGENT);
}
__device__ __forceinline__ void stg8(unsigned char* p, unsigned char v) {
    __hip_atomic_store(p, v, __ATOMIC_RELAXED, __HIP_MEMORY_SCOPE_AGENT);
}
__device__ __forceinline__ int ldga(const int* p) {
    return __hip_atomic_load((int*)p, __ATOMIC_RELAXED, __HIP_MEMORY_SCOPE_AGENT);
}

// ---- init: zero deg/need/cnt/bar/agg1/agg2, -1 the s1 index map ----
__global__ void prek(int* deg, int* s1idx, unsigned char* need,
                     float* agg1, float* agg2, int* cnt, int* bar) {
    int n = blockIdx.x * blockDim.x + threadIdx.x;   // grid covers 524288
    if (n < NNODES) { deg[n] = 0; s1idx[n] = -1; need[n] = 0; }
    if (n < CAP1 * D) agg1[n] = 0.0f;
    if (n < NGRAPH * D) agg2[n] = 0.0f;
    if (n < 8) cnt[n] = 0;
    if (n < 3 * BLINES * 16) bar[n] = 0;
}

// ---- fence-free grid barrier: all cross-barrier data goes via coherent ops ----
__device__ __forceinline__ void gridbar(int* bar, int bi) {
    __syncthreads();
    if (threadIdx.x == 0) {
        asm volatile("s_waitcnt vmcnt(0) lgkmcnt(0)" ::: "memory");  // my stores are at IC
        atomicAdd(&bar[bi * BLINES * 16 + (blockIdx.x & (BLINES - 1)) * 16], 1);
        int s;
        do {
            s = 0;
            #pragma unroll
            for (int i = 0; i < BLINES; i++)
                s += __hip_atomic_load(&bar[bi * BLINES * 16 + i * 16],
                                       __ATOMIC_RELAXED, __HIP_MEMORY_SCOPE_AGENT);
            if (s < NBLK) __builtin_amdgcn_s_sleep(2);
        } while (s < NBLK);
    }
    __syncthreads();
    asm volatile("" ::: "memory");                   // compiler-only fence (free)
}

// ---- fused scans A (e2 edges + S1 dedup), B (e1 edges + need), C (degrees),
//      and agg1 (feature gather-aggregate). 3 internal barriers. ----
__global__ __launch_bounds__(256, 4) void megascan(
        const int* __restrict__ src, const int4* __restrict__ dst4,
        const int* __restrict__ to_fetch, const float* __restrict__ feat,
        int* e2src, int* e2slot, int* s1idx, int* s1nodes, unsigned char* need,
        int* e1src, int* e1j, int* deg, float* agg1, int* cnt, int* bar) {

    const int tid = threadIdx.x;
    const int bid = blockIdx.x;
    const int NV = NEDGES / 4;
    const int stride = NBLK * 256;

    __shared__ int tf[NGRAPH];
    __shared__ int lcnt, lbase;
    __shared__ int bufs[FBUF], bufj[FBUF];

    // ========== phase A: edges into fetched nodes; inline-dedup S1 sources ======
    for (int i = tid; i < NGRAPH; i += 256) tf[i] = to_fetch[i];
    if (tid == 0) lcnt = 0;
    __syncthreads();
    if (bid == 0 && tid < NGRAPH) stg8(&need[tf[tid] + tid * NPG], 1);
    for (int v = bid * 256 + tid; v < NV; v += stride) {
        int4 d4 = dst4[v];
        int ds[4] = {d4.x, d4.y, d4.z, d4.w};
        #pragma unroll
        for (int q = 0; q < 4; ++q) {
            int d = ds[q];
            int slot = d / NPG;                       // magic-mul division
            if (tf[slot] == d - slot * NPG) {
                int s = src[v * 4 + q];
                int p = atomicAdd(&lcnt, 1);
                if (p < FBUF) { bufs[p] = s; bufj[p] = slot; }
                bool win = (atomicCAS(&s1idx[s], -1, -2) == -1);   // coherent RMW
                unsigned long long mask = __ballot(win ? 1 : 0);
                if (mask) {
                    int lane = tid & 63;
                    int lead = __ffsll(mask) - 1;
                    int nw = __popcll(mask);
                    int base = 0;
                    if (lane == lead) base = atomicAdd(&cnt[1], nw);
                    base = __shfl(base, lead, 64);
                    if (win) {
                        int idx = base + __popcll(mask & ((1ull << lane) - 1ull));
                        if (idx < CAP1) {
                            stg(&s1idx[s], idx);       // coherent store (crosses barrier)
                            s1nodes[idx] = s;          // plain: read only by later kernels
                            stg8(&need[s], 1);
                        } else stg(&s1idx[s], -1);
                    }
                }
            }
        }
    }
    __syncthreads();
    {
        int n = min(lcnt, FBUF);
        if (tid == 0) lbase = atomicAdd(&cnt[0], n);
        __syncthreads();
        for (int k = tid; k < n; k += 256) {
            int g = lbase + k;
            if (g < CAP2) { e2src[g] = bufs[k]; e2slot[g] = bufj[k]; }  // plain: later kernels
        }
        __syncthreads();
        if (tid == 0) lcnt = 0;
    }
    gridbar(bar, 0);

    // ========== phase B: edges into S1 nodes; flag sources needed ===============
    // s1idx lines were never plain-accessed in this kernel -> plain gather is fresh
    for (int v = bid * 256 + tid; v < NV; v += stride) {
        int4 d4 = dst4[v];
        int ds[4] = {d4.x, d4.y, d4.z, d4.w};
        #pragma unroll
        for (int q = 0; q < 4; ++q) {
            int j = s1idx[ds[q]];
            if (j >= 0) {
                int s = src[v * 4 + q];
                stg8(&need[s], 1);                    // coherent (crosses barrier)
                int p = atomicAdd(&lcnt, 1);
                if (p < FBUF) { bufs[p] = s; bufj[p] = j; }
            }
        }
    }
    __syncthreads();
    {
        int n = min(lcnt, FBUF);                      // expected ~33/block
        if (tid == 0) lbase = atomicAdd(&cnt[2], n);
        __syncthreads();
        for (int k = tid; k < n; k += 256) {
            int g = lbase + k;
            if (g < CAPE) { stg(&e1src[g], bufs[k]); stg(&e1j[g], bufj[k]); }  // read post-bar
        }
    }
    gridbar(bar, 1);

    // ========== phase C: degrees of needed nodes (~27K of 200K) =================
    // need lines never plain-accessed before -> plain loads fresh
    for (int v = bid * 256 + tid; v < NV; v += stride) {
        int4 d4 = dst4[v];
        int ds[4] = {d4.x, d4.y, d4.z, d4.w};
        #pragma unroll
        for (int q = 0; q < 4; ++q)
            if (need[ds[q]]) atomicAdd(&deg[ds[q]], 1);
    }
    gridbar(bar, 2);

    // ========== phase agg1: agg1[j] += feat[s]*rsqrt(max(deg[s],1)) =============
    {
        int ne = min(ldga(&cnt[2]), CAPE);
        int col = tid & 127, sub = tid >> 7;          // 2 edge-lanes per block
        for (int e = bid * 2 + sub; e < ne; e += NBLK * 2) {
            int s = e1src[e];                         // plain: first touch post-barrier
            int j = e1j[e];
            float nm = rsqrtf(fmaxf((float)deg[s], 1.0f));   // deg never plain-touched before
            float v = feat[(size_t)s * D + col] * nm;
            atomicAdd(&agg1[j * D + col], v);
        }
    }
}

// ---- layer-1 GEMM + relu + pre-multiply next-layer norm ----
__global__ void gemm1(const float* __restrict__ agg1, const float* __restrict__ w1,
                      const float* __restrict__ b1, const int* __restrict__ deg,
                      const int* __restrict__ s1nodes, const int* __restrict__ cnt,
                      float* h1n) {
    int nj = min(cnt[1], CAP1);
    int t = threadIdx.x;                 // 128
    __shared__ float sa[D];
    for (int j = blockIdx.x; j < nj; j += gridDim.x) {
        __syncthreads();
        sa[t] = agg1[j * D + t];
        __syncthreads();
        float acc = 0.0f;
        #pragma unroll
        for (int k = 0; k < D; k++) acc += sa[k] * w1[k * D + t];
        float nm = rsqrtf(fmaxf((float)deg[s1nodes[j]], 1.0f));
        h1n[j * D + t] = fmaxf(acc * nm + b1[t], 0.0f) * nm;
    }
}

// ---- layer-2 aggregation over the ~1600 fetched-node edges ----
__global__ void agg2_kernel(const int* __restrict__ e2src, const int* __restrict__ e2slot,
                            const int* __restrict__ s1idx, const int* __restrict__ cnt,
                            const float* __restrict__ h1n, float* agg2) {
    int t = threadIdx.x;                 // 128
    int ne = min(cnt[0], CAP2);
    for (int e = blockIdx.x; e < ne; e += gridDim.x) {
        int j = s1idx[e2src[e]];
        if (j >= 0) atomicAdd(&agg2[e2slot[e] * D + t], h1n[j * D + t]);
    }
}

// ---- layer-2 GEMM + relu, then out = h2 @ w3^T + b3 ----
__global__ void final_kernel(const float* __restrict__ agg2, const float* __restrict__ w2,
                             const float* __restrict__ b2, const int* __restrict__ deg,
                             const int* __restrict__ to_fetch,
                             const float* __restrict__ w3, const float* __restrict__ b3,
                             float* out) {
    int i = blockIdx.x;                  // 0..99
    int t = threadIdx.x;                 // 128
    __shared__ float sa[D], h2[D];
    sa[t] = agg2[i * D + t];
    __syncthreads();
    float acc = 0.0f;
    #pragma unroll
    for (int k = 0; k < D; k++) acc += sa[k] * w2[k * D + t];
    float nm = rsqrtf(fmaxf((float)deg[to_fetch[i] + i * NPG], 1.0f));
    h2[t] = fmaxf(acc * nm + b2[t], 0.0f);
    __syncthreads();
    if (t < DOUT) {
        float o = 0.0f;
        #pragma unroll
        for (int k = 0; k < D; k++) o += h2[k] * w3[t * D + k];
        out[i * DOUT + t] = o + b3[t];
    }
}

extern "C" void kernel_launch(void* const* d_in, const int* in_sizes, int n_in,
                              void* d_out, int out_size, void* d_ws, size_t ws_size,
                              hipStream_t stream) {
    const float* feat     = (const float*)d_in[0];
    const int*   src      = (const int*)  d_in[1];
    const int*   dst      = (const int*)  d_in[2];
    const int*   to_fetch = (const int*)  d_in[3];
    const float* w1       = (const float*)d_in[4];
    const float* b1       = (const float*)d_in[5];
    const float* w2       = (const float*)d_in[6];
    const float* b2       = (const float*)d_in[7];
    const float* w3       = (const float*)d_in[8];
    const float* b3       = (const float*)d_in[9];
    float* out = (float*)d_out;
    const int4* dst4 = (const int4*)dst;

    // workspace layout
    char* p = (char*)d_ws;
    int*   deg     = (int*)p;            p += (size_t)NNODES * 4;
    int*   s1idx   = (int*)p;            p += (size_t)NNODES * 4;
    int*   s1nodes = (int*)p;            p += (size_t)CAP1 * 4;
    int*   e2src   = (int*)p;            p += (size_t)CAP2 * 4;
    int*   e2slot  = (int*)p;            p += (size_t)CAP2 * 4;
    int*   e1src   = (int*)p;            p += (size_t)CAPE * 4;
    int*   e1j     = (int*)p;            p += (size_t)CAPE * 4;
    float* agg1    = (float*)p;          p += (size_t)CAP1 * D * 4;
    float* h1n     = (float*)p;          p += (size_t)CAP1 * D * 4;
    float* agg2    = (float*)p;          p += (size_t)NGRAPH * D * 4;
    int*   cnt     = (int*)p;            p += 64;
    int*   bar     = (int*)p;            p += 3 * BLINES * 16 * 4;
    unsigned char* need = (unsigned char*)p; p += (size_t)NNODES;

    prek<<<(CAP1 * D + 255) / 256, 256, 0, stream>>>(deg, s1idx, need, agg1, agg2, cnt, bar);
    megascan<<<NBLK, 256, 0, stream>>>(src, dst4, to_fetch, feat,
                                       e2src, e2slot, s1idx, s1nodes, need,
                                       e1src, e1j, deg, agg1, cnt, bar);
    gemm1<<<CAP1, 128, 0, stream>>>(agg1, w1, b1, deg, s1nodes, cnt, h1n);
    agg2_kernel<<<1024, 128, 0, stream>>>(e2src, e2slot, s1idx, cnt, h1n, agg2);
    final_kernel<<<NGRAPH, 128, 0, stream>>>(agg2, w2, b2, deg, to_fetch, w3, b3, out);
}

// Round 11
// 133.758 us; speedup vs baseline: 1.6784x; 1.6784x over previous
//
#include <hip/hip_runtime.h>

#define NNODES 200000
#define NEDGES 3200000
#define NGRAPH 100
#define NPG    2000
#define D      128
#define DOUT   64
#define CAP1   4096     // max distinct layer-1 nodes (expected ~1600)
#define CAP2   8192     // max edges into fetched nodes (expected ~1600)
#define CAPE   65536    // max edges into S1 nodes (expected ~25600)
#define FBUF   512      // per-block LDS compaction buffer
#define BMW    6250     // bitmap words: 200000 bits / 32

// ---- init: zero deg/bitmaps/counters/agg1/agg2, -1 the s1 index map ----
__global__ void prek(int* deg, int* s1idx, int* s1bits, int* needbits,
                     float* agg1, float* agg2, int* cnt) {
    int n = blockIdx.x * blockDim.x + threadIdx.x;   // grid covers 524288
    if (n < NNODES) { deg[n] = 0; s1idx[n] = -1; }
    if (n < CAP1 * D) agg1[n] = 0.0f;
    if (n < NGRAPH * D) agg2[n] = 0.0f;
    if (n < BMW) { s1bits[n] = 0; needbits[n] = 0; }
    if (n < 8) cnt[n] = 0;
}

// ---- scan 1: edges into fetched nodes (arithmetic membership),
//      collect (src,slot), inline-dedup sources, build s1/need bitmaps ----
__global__ __launch_bounds__(256) void passA(
        const int* __restrict__ src, const int4* __restrict__ dst4,
        const int* __restrict__ to_fetch,
        int* e2src, int* e2slot, int* s1idx, int* s1nodes,
        int* s1bits, int* needbits, int* cnt) {
    __shared__ int tf[NGRAPH];
    __shared__ int lcnt, lbase;
    __shared__ int bufs[FBUF], bufj[FBUF];
    int tid = threadIdx.x;
    for (int i = tid; i < NGRAPH; i += blockDim.x) tf[i] = to_fetch[i];
    if (tid == 0) lcnt = 0;
    __syncthreads();
    if (blockIdx.x == 0 && tid < NGRAPH) {
        int n2 = tf[tid] + tid * NPG;                 // fetched nodes need their norm
        atomicOr(&needbits[n2 >> 5], 1 << (n2 & 31));
    }
    const int NV = NEDGES / 4;
    int stride = gridDim.x * blockDim.x;
    for (int v = blockIdx.x * blockDim.x + tid; v < NV; v += stride) {
        int4 d4 = dst4[v];
        int ds[4] = {d4.x, d4.y, d4.z, d4.w};
        #pragma unroll
        for (int q = 0; q < 4; ++q) {
            int d = ds[q];
            int slot = d / NPG;                       // magic-mul division
            if (tf[slot] == d - slot * NPG) {
                int s = src[v * 4 + q];
                int p = atomicAdd(&lcnt, 1);
                if (p < FBUF) { bufs[p] = s; bufj[p] = slot; }
                bool win = (atomicCAS(&s1idx[s], -1, -2) == -1);
                unsigned long long mask = __ballot(win ? 1 : 0);
                if (mask) {
                    int lane = tid & 63;
                    int lead = __ffsll(mask) - 1;
                    int nw = __popcll(mask);
                    int base = 0;
                    if (lane == lead) base = atomicAdd(&cnt[1], nw);
                    base = __shfl(base, lead, 64);
                    if (win) {
                        int idx = base + __popcll(mask & ((1ull << lane) - 1ull));
                        if (idx < CAP1) {
                            s1idx[s] = idx; s1nodes[idx] = s;
                            atomicOr(&s1bits[s >> 5], 1 << (s & 31));
                            atomicOr(&needbits[s >> 5], 1 << (s & 31));
                        } else s1idx[s] = -1;
                    }
                }
            }
        }
    }
    __syncthreads();
    {
        int n = min(lcnt, FBUF);
        if (tid == 0) lbase = atomicAdd(&cnt[0], n);
        __syncthreads();
        for (int k = tid; k < n; k += blockDim.x) {
            int g = lbase + k;
            if (g < CAP2) { e2src[g] = bufs[k]; e2slot[g] = bufj[k]; }
        }
    }
}

// ---- scan 2: membership via LDS bitmap; collect e1 edges, mark sources needed ----
__global__ __launch_bounds__(512) void passB(
        const int* __restrict__ src, const int4* __restrict__ dst4,
        const int* __restrict__ s1bits, const int* __restrict__ s1idx,
        int* needbits, int* e1src, int* e1j, int* cnt) {
    __shared__ int bm[BMW];
    __shared__ int lcnt, lbase;
    __shared__ int bufs[FBUF], bufj[FBUF];
    int tid = threadIdx.x;
    for (int i = tid; i < BMW; i += blockDim.x) bm[i] = s1bits[i];
    if (tid == 0) lcnt = 0;
    __syncthreads();
    const int NV = NEDGES / 4;
    int stride = gridDim.x * blockDim.x;
    for (int v = blockIdx.x * blockDim.x + tid; v < NV; v += stride) {
        int4 d4 = dst4[v];
        int ds[4] = {d4.x, d4.y, d4.z, d4.w};
        #pragma unroll
        for (int q = 0; q < 4; ++q) {
            int d = ds[q];
            if (bm[d >> 5] & (1 << (d & 31))) {       // LDS test, exact
                int j = s1idx[d];                      // L2 gather, true hits only
                int s = src[v * 4 + q];
                atomicOr(&needbits[s >> 5], 1 << (s & 31));
                int p = atomicAdd(&lcnt, 1);
                if (p < FBUF) { bufs[p] = s; bufj[p] = j; }
            }
        }
    }
    __syncthreads();
    {
        int n = min(lcnt, FBUF);                      // expected ~25/block
        if (tid == 0) lbase = atomicAdd(&cnt[2], n);
        __syncthreads();
        for (int k = tid; k < n; k += blockDim.x) {
            int g = lbase + k;
            if (g < CAPE) { e1src[g] = bufs[k]; e1j[g] = bufj[k]; }
        }
    }
}

// ---- scan 3: degree count for needed nodes, membership via LDS bitmap ----
__global__ __launch_bounds__(512) void passC(
        const int4* __restrict__ dst4, const int* __restrict__ needbits, int* deg) {
    __shared__ int bm[BMW];
    int tid = threadIdx.x;
    for (int i = tid; i < BMW; i += blockDim.x) bm[i] = needbits[i];
    __syncthreads();
    const int NV = NEDGES / 4;
    int stride = gridDim.x * blockDim.x;
    for (int v = blockIdx.x * blockDim.x + tid; v < NV; v += stride) {
        int4 d4 = dst4[v];
        int ds[4] = {d4.x, d4.y, d4.z, d4.w};
        #pragma unroll
        for (int q = 0; q < 4; ++q) {
            int d = ds[q];
            if (bm[d >> 5] & (1 << (d & 31))) atomicAdd(&deg[d], 1);
        }
    }
}

// ---- layer-1 aggregation: agg1[j] += feat[s]*rsqrt(max(deg[s],1)) ----
__global__ void agg1_kernel(const int* __restrict__ e1src, const int* __restrict__ e1j,
                            const int* __restrict__ cnt, const int* __restrict__ deg,
                            const float* __restrict__ feat, float* agg1) {
    int col = threadIdx.x & 127, sub = threadIdx.x >> 7;   // 256 thr = 2 edge-lanes
    int ne = min(cnt[2], CAPE);
    for (int e = blockIdx.x * 2 + sub; e < ne; e += gridDim.x * 2) {
        int s = e1src[e];
        float nm = rsqrtf(fmaxf((float)deg[s], 1.0f));
        float v = feat[(size_t)s * D + col] * nm;
        atomicAdd(&agg1[e1j[e] * D + col], v);
    }
}

// ---- layer-1 GEMM + relu + pre-multiply next-layer norm ----
__global__ void gemm1(const float* __restrict__ agg1, const float* __restrict__ w1,
                      const float* __restrict__ b1, const int* __restrict__ deg,
                      const int* __restrict__ s1nodes, const int* __restrict__ cnt,
                      float* h1n) {
    int nj = min(cnt[1], CAP1);
    int t = threadIdx.x;                 // 128
    __shared__ float sa[D];
    for (int j = blockIdx.x; j < nj; j += gridDim.x) {
        __syncthreads();
        sa[t] = agg1[j * D + t];
        __syncthreads();
        float acc = 0.0f;
        #pragma unroll
        for (int k = 0; k < D; k++) acc += sa[k] * w1[k * D + t];
        float nm = rsqrtf(fmaxf((float)deg[s1nodes[j]], 1.0f));
        h1n[j * D + t] = fmaxf(acc * nm + b1[t], 0.0f) * nm;
    }
}

// ---- layer-2 aggregation over the ~1600 fetched-node edges ----
__global__ void agg2_kernel(const int* __restrict__ e2src, const int* __restrict__ e2slot,
                            const int* __restrict__ s1idx, const int* __restrict__ cnt,
                            const float* __restrict__ h1n, float* agg2) {
    int t = threadIdx.x;                 // 128
    int ne = min(cnt[0], CAP2);
    for (int e = blockIdx.x; e < ne; e += gridDim.x) {
        int j = s1idx[e2src[e]];
        if (j >= 0) atomicAdd(&agg2[e2slot[e] * D + t], h1n[j * D + t]);
    }
}

// ---- layer-2 GEMM + relu, then out = h2 @ w3^T + b3 ----
__global__ void final_kernel(const float* __restrict__ agg2, const float* __restrict__ w2,
                             const float* __restrict__ b2, const int* __restrict__ deg,
                             const int* __restrict__ to_fetch,
                             const float* __restrict__ w3, const float* __restrict__ b3,
                             float* out) {
    int i = blockIdx.x;                  // 0..99
    int t = threadIdx.x;                 // 128
    __shared__ float sa[D], h2[D];
    sa[t] = agg2[i * D + t];
    __syncthreads();
    float acc = 0.0f;
    #pragma unroll
    for (int k = 0; k < D; k++) acc += sa[k] * w2[k * D + t];
    float nm = rsqrtf(fmaxf((float)deg[to_fetch[i] + i * NPG], 1.0f));
    h2[t] = fmaxf(acc * nm + b2[t], 0.0f);
    __syncthreads();
    if (t < DOUT) {
        float o = 0.0f;
        #pragma unroll
        for (int k = 0; k < D; k++) o += h2[k] * w3[t * D + k];
        out[i * DOUT + t] = o + b3[t];
    }
}

extern "C" void kernel_launch(void* const* d_in, const int* in_sizes, int n_in,
                              void* d_out, int out_size, void* d_ws, size_t ws_size,
                              hipStream_t stream) {
    const float* feat     = (const float*)d_in[0];
    const int*   src      = (const int*)  d_in[1];
    const int*   dst      = (const int*)  d_in[2];
    const int*   to_fetch = (const int*)  d_in[3];
    const float* w1       = (const float*)d_in[4];
    const float* b1       = (const float*)d_in[5];
    const float* w2       = (const float*)d_in[6];
    const float* b2       = (const float*)d_in[7];
    const float* w3       = (const float*)d_in[8];
    const float* b3       = (const float*)d_in[9];
    float* out = (float*)d_out;
    const int4* dst4 = (const int4*)dst;

    // workspace layout
    char* p = (char*)d_ws;
    int*   deg      = (int*)p;           p += (size_t)NNODES * 4;
    int*   s1idx    = (int*)p;           p += (size_t)NNODES * 4;
    int*   s1nodes  = (int*)p;           p += (size_t)CAP1 * 4;
    int*   e2src    = (int*)p;           p += (size_t)CAP2 * 4;
    int*   e2slot   = (int*)p;           p += (size_t)CAP2 * 4;
    int*   e1src    = (int*)p;           p += (size_t)CAPE * 4;
    int*   e1j      = (int*)p;           p += (size_t)CAPE * 4;
    float* agg1     = (float*)p;         p += (size_t)CAP1 * D * 4;
    float* h1n      = (float*)p;         p += (size_t)CAP1 * D * 4;
    float* agg2     = (float*)p;         p += (size_t)NGRAPH * D * 4;
    int*   s1bits   = (int*)p;           p += (size_t)BMW * 4;
    int*   needbits = (int*)p;           p += (size_t)BMW * 4;
    int*   cnt      = (int*)p;           p += 64;

    prek<<<(CAP1 * D + 255) / 256, 256, 0, stream>>>(deg, s1idx, s1bits, needbits,
                                                     agg1, agg2, cnt);
    passA<<<2048, 256, 0, stream>>>(src, dst4, to_fetch, e2src, e2slot,
                                    s1idx, s1nodes, s1bits, needbits, cnt);
    passB<<<1024, 512, 0, stream>>>(src, dst4, s1bits, s1idx, needbits,
                                    e1src, e1j, cnt);
    passC<<<1024, 512, 0, stream>>>(dst4, needbits, deg);
    agg1_kernel<<<2048, 256, 0, stream>>>(e1src, e1j, cnt, deg, feat, agg1);
    gemm1<<<CAP1, 128, 0, stream>>>(agg1, w1, b1, deg, s1nodes, cnt, h1n);
    agg2_kernel<<<1024, 128, 0, stream>>>(e2src, e2slot, s1idx, cnt, h1n, agg2);
    final_kernel<<<NGRAPH, 128, 0, stream>>>(agg2, w2, b2, deg, to_fetch, w3, b3, out);
}